// Round 3
// baseline (3445.326 us; speedup 1.0000x reference)
//
#include <hip/hip_runtime.h>
#include <math.h>

#define N 8192
#define D 256
#define KP 272          // j-panel width in bf16: 256 data + 16 ext (pot hi/lo at 256,257)
#define LN2 0.6931471805599453f

typedef short short8 __attribute__((ext_vector_type(8)));
typedef float f32x16 __attribute__((ext_vector_type(16)));
typedef unsigned short ushort;

__device__ __forceinline__ float fexp2(float x) { return __builtin_amdgcn_exp2f(x); }
__device__ __forceinline__ float flog2(float x) { return __builtin_amdgcn_logf(x); }

__device__ __forceinline__ ushort bf16r(float x) {  // RNE f32 -> bf16
    unsigned int u = __float_as_uint(x);
    return (ushort)((u + 0x7FFF + ((u >> 16) & 1)) >> 16);
}
__device__ __forceinline__ float bf16f(ushort h) {
    return __uint_as_float(((unsigned int)h) << 16);
}

// ---------------- weight clip + renormalize ----------------
__global__ void prep_wc(const float* __restrict__ w, float* __restrict__ wc) {
    int t = threadIdx.x;  // 256
    float v = fminf(fmaxf(w[t], 0.0f), 2.0f);
    float s = v;
#pragma unroll
    for (int m = 1; m < 64; m <<= 1) s += __shfl_xor(s, m);
    __shared__ float sm[4];
    if ((t & 63) == 0) sm[t >> 6] = s;
    __syncthreads();
    float mean = (sm[0] + sm[1] + sm[2] + sm[3]) * (1.0f / 256.0f);
    wc[t] = v / mean;
}

// ---------------- normalize rows, emit bf16 i-panels + j-panels ----------------
__global__ void prep_normalize(const float* __restrict__ x1, const float* __restrict__ x2,
                               const float* __restrict__ wc,
                               ushort* __restrict__ an_i, ushort* __restrict__ bn_i,
                               ushort* __restrict__ pan0, ushort* __restrict__ pan1,
                               ushort* __restrict__ pan2, ushort* __restrict__ pan3) {
    int row = blockIdx.x;  // 0..16383
    int t = threadIdx.x;   // 0..255
    int r; float v;
    ushort *ip, *pa, *pb;
    if (row < N) { r = row;     v = x1[(size_t)r * D + t] * wc[t]; ip = an_i; pa = pan0; pb = pan3; }
    else         { r = row - N; v = x2[(size_t)r * D + t];         ip = bn_i; pa = pan1; pb = pan2; }
    float ss = v * v;
#pragma unroll
    for (int m = 1; m < 64; m <<= 1) ss += __shfl_xor(ss, m);
    __shared__ float sm[4];
    if ((t & 63) == 0) sm[t >> 6] = ss;
    __syncthreads();
    float denom = sqrtf(sm[0] + sm[1] + sm[2] + sm[3]) + 1e-12f;
    ushort b = bf16r(v / denom);
    ip[(size_t)r * D + t] = b;
    pa[(size_t)r * KP + t] = b;
    pb[(size_t)r * KP + t] = b;
    if (t < 16) {  // ext cols: pot=0 -> pterm=-1 -> hi=0xBF80, lo=0; cols 258..271 zero
        ushort e = (t == 0) ? (ushort)0xBF80 : (ushort)0;
        pa[(size_t)r * KP + 256 + t] = e;
        pb[(size_t)r * KP + 256 + t] = e;
    }
}

// ---------------- fused cost + softmin via MFMA (flash-style, no LDS) ----------------
// tasks: 0: fxx (j=an, pot=fxx)  1: gyy (j=bn, pot=gyy)  2: f (j=bn, pot=g)  3: g (j=an, pot=f)
// One 32x32 acc tile per wave: i-frags (17 short8 = 68 VGPR) stay resident; 4 waves/SIMD.
// Block mapping keeps (task, split) constant per XCD (bx % 8) for L2 panel reuse.
__global__ __launch_bounds__(256, 4) void softmin_mfma(
    const ushort* __restrict__ an_i, const ushort* __restrict__ bn_i,
    const ushort* __restrict__ pan0, const ushort* __restrict__ pan1,
    const ushort* __restrict__ pan2, const ushort* __restrict__ pan3,
    float2* __restrict__ parts, float k1) {  // k1 = log2(e)/eps
    int bx = blockIdx.x;          // 1024 blocks
    int k = bx & 7;               // XCD slot (heuristic)
    int q = bx >> 3;              // 0..127
    int task = k >> 1;
    int split = ((k & 1) << 1) | (q & 1);
    int rb = q >> 1;              // 0..63
    const ushort* jp; const ushort* ip;
    switch (task) {
        case 0:  jp = pan0; ip = an_i; break;
        case 1:  jp = pan1; ip = bn_i; break;
        case 2:  jp = pan2; ip = an_i; break;
        default: jp = pan3; ip = bn_i; break;
    }
    int t = threadIdx.x;
    int wave = t >> 6, lane = t & 63;
    int l31 = lane & 31, lh = lane >> 5;
    int i0 = rb * 128 + wave * 32;  // this wave: rows [i0, i0+32)

    // B_op (i-side) fragments, K=256 (16 chunks) + pot chunk
    short8 bi[17];
    const ushort* ib = ip + (size_t)(i0 + l31) * D + lh * 8;
#pragma unroll
    for (int c = 0; c < 16; ++c) bi[c] = *(const short8*)(ib + c * 16);
    short8 pz = {};  // pot chunk: a_ext[i][256]=a_ext[i][257]=1.0
    if (lh == 0) { pz[0] = (short)0x3F80; pz[1] = (short)0x3F80; }
    bi[16] = pz;

    float m0 = -INFINITY, s0 = 0.0f;
    const ushort* jbase = jp + (size_t)(split * 2048 + l31) * KP + lh * 8;

    for (int js = 0; js < 64; ++js) {  // 32 j's per step, 2048 per split
        const ushort* ar = jbase + (size_t)js * 32 * KP;
        f32x16 acc = {};
#pragma unroll
        for (int c = 0; c < 17; ++c) {
            short8 af = *(const short8*)(ar + c * 16);
            acc = __builtin_amdgcn_mfma_f32_32x32x16_bf16(af, bi[c], acc, 0, 0, 0);
        }
        // acc = cos_sim + (pot_j - 1); online LSE in base-2, per lane (one row)
        float tv[16];
#pragma unroll
        for (int r = 0; r < 16; ++r) tv[r] = acc[r] * k1;
        float tm = tv[0];
#pragma unroll
        for (int r = 1; r < 16; ++r) tm = fmaxf(tm, tv[r]);
        float mn = fmaxf(m0, tm);
        float ad = 0.0f;
#pragma unroll
        for (int r = 0; r < 16; ++r) ad += fexp2(tv[r] - mn);
        s0 = s0 * fexp2(m0 - mn) + ad; m0 = mn;
    }
    // lanes l and l+32 hold disjoint j-subsets of the same row: merge
    float mo = __shfl_xor(m0, 32), so = __shfl_xor(s0, 32);
    float M0 = fmaxf(m0, mo);
    float S0 = s0 * fexp2(m0 - M0) + so * fexp2(mo - M0);
    if (lane < 32) {
        size_t r0 = (size_t)task * N + (i0 + l31);
        parts[r0 * 4 + split] = make_float2(M0, S0);
    }
}

// ---------------- merge j-split partials -> new potentials + panel pot columns ----------------
__global__ void merge_pots(const float2* __restrict__ parts, float* __restrict__ pots,
                           ushort* __restrict__ pan0, ushort* __restrict__ pan1,
                           ushort* __restrict__ pan2, ushort* __restrict__ pan3,
                           float eps, float logw, int do_avg) {
    int id = blockIdx.x * 256 + threadIdx.x;  // 0..4N-1; id = task*N + row
    int task = id >> 13;
    int row = id & (N - 1);
    const float2* p = parts + (size_t)id * 4;
    float2 a = p[0], b = p[1], c = p[2], d = p[3];
    float M = fmaxf(fmaxf(a.x, b.x), fmaxf(c.x, d.x));
    float S = a.y * fexp2(a.x - M) + b.y * fexp2(b.x - M) +
              c.y * fexp2(c.x - M) + d.y * fexp2(d.x - M);
    float lse = LN2 * (M + flog2(S));      // natural-log LSE of (pot_j - C_ij)/eps
    float v = -eps * (logw + lse);
    if (do_avg && task < 2) v = 0.5f * (pots[id] + v);
    pots[id] = v;
    // panel pot columns for NEXT iteration: task0->pan0, task1->pan1,
    // task2 (f) -> pan3 (task3 streams f), task3 (g) -> pan2 (task2 streams g)
    ushort* pan;
    switch (task) {
        case 0:  pan = pan0; break;
        case 1:  pan = pan1; break;
        case 2:  pan = pan3; break;
        default: pan = pan2; break;
    }
    float pt = v - 1.0f;
    ushort hi = bf16r(pt);
    float lo = pt - bf16f(hi);
    pan[(size_t)row * KP + 256] = hi;
    pan[(size_t)row * KP + 257] = bf16r(lo);
}

// ---------------- final scalar reduce ----------------
__global__ void final_reduce(const float* __restrict__ pots, float* __restrict__ out) {
    int t = threadIdx.x;
    float s = 0.0f;
    for (int i = t; i < N; i += 256)
        s += (pots[2 * N + i] - pots[i]) + (pots[3 * N + i] - pots[N + i]);
#pragma unroll
    for (int m = 1; m < 64; m <<= 1) s += __shfl_xor(s, m);
    __shared__ float sm[4];
    if ((t & 63) == 0) sm[t >> 6] = s;
    __syncthreads();
    if (t == 0) out[0] = (sm[0] + sm[1] + sm[2] + sm[3]) * (1.0f / (float)N);
}

extern "C" void kernel_launch(void* const* d_in, const int* in_sizes, int n_in,
                              void* d_out, int out_size, void* d_ws, size_t ws_size,
                              hipStream_t stream) {
    const float* x1 = (const float*)d_in[0];
    const float* x2 = (const float*)d_in[1];
    const float* w  = (const float*)d_in[2];
    float* out = (float*)d_out;

    ushort* an_i = (ushort*)d_ws;                       // N*D bf16
    ushort* bn_i = an_i + (size_t)N * D;                // N*D
    ushort* pan0 = bn_i + (size_t)N * D;                // N*KP each
    ushort* pan1 = pan0 + (size_t)N * KP;
    ushort* pan2 = pan1 + (size_t)N * KP;
    ushort* pan3 = pan2 + (size_t)N * KP;
    float*  wc   = (float*)(pan3 + (size_t)N * KP);     // 256
    float*  pots = wc + 256;                            // 4N  (fxx,gyy,f,g)
    float2* parts = (float2*)(pots + 4 * N);            // 4N * 4 splits

    hipMemsetAsync(pots, 0, 4 * N * sizeof(float), stream);
    prep_wc<<<1, 256, 0, stream>>>(w, wc);
    prep_normalize<<<2 * N, 256, 0, stream>>>(x1, x2, wc, an_i, bn_i, pan0, pan1, pan2, pan3);

    const float eps_list[10] = {4.0f, 1.0f, 0.25f, 0.0625f, 0.015625f,
                                0.00390625f, 0.0025f, 0.0025f, 0.0025f, 0.0025f};
    const float logw = -logf((float)N);
    const float LOG2E = 1.4426950408889634f;
    for (int it = 0; it < 10; ++it) {
        softmin_mfma<<<1024, 256, 0, stream>>>(an_i, bn_i, pan0, pan1, pan2, pan3,
                                               parts, LOG2E / eps_list[it]);
        merge_pots<<<4 * N / 256, 256, 0, stream>>>(parts, pots, pan0, pan1, pan2, pan3,
                                                    eps_list[it], logw, 1);
    }
    // final extrapolation at eps_final, no averaging
    softmin_mfma<<<1024, 256, 0, stream>>>(an_i, bn_i, pan0, pan1, pan2, pan3,
                                           parts, LOG2E / 0.0025f);
    merge_pots<<<4 * N / 256, 256, 0, stream>>>(parts, pots, pan0, pan1, pan2, pan3,
                                                0.0025f, logw, 0);
    final_reduce<<<1, 256, 0, stream>>>(pots, out);
}

// Round 4
// 2194.464 us; speedup vs baseline: 1.5700x; 1.5700x over previous
//
#include <hip/hip_runtime.h>
#include <math.h>

#define N 8192
#define D 256
#define KP 272          // j-panel width in bf16: 256 data + 16 ext (pot hi/lo at 256,257)
#define LN2 0.6931471805599453f

typedef short short8 __attribute__((ext_vector_type(8)));
typedef float f32x16 __attribute__((ext_vector_type(16)));
typedef unsigned short ushort;

__device__ __forceinline__ float fexp2(float x) { return __builtin_amdgcn_exp2f(x); }
__device__ __forceinline__ float flog2(float x) { return __builtin_amdgcn_logf(x); }

__device__ __forceinline__ ushort bf16r(float x) {  // RNE f32 -> bf16
    unsigned int u = __float_as_uint(x);
    return (ushort)((u + 0x7FFF + ((u >> 16) & 1)) >> 16);
}
__device__ __forceinline__ float bf16f(ushort h) {
    return __uint_as_float(((unsigned int)h) << 16);
}

// ---------------- weight clip + renormalize ----------------
__global__ void prep_wc(const float* __restrict__ w, float* __restrict__ wc) {
    int t = threadIdx.x;  // 256
    float v = fminf(fmaxf(w[t], 0.0f), 2.0f);
    float s = v;
#pragma unroll
    for (int m = 1; m < 64; m <<= 1) s += __shfl_xor(s, m);
    __shared__ float sm[4];
    if ((t & 63) == 0) sm[t >> 6] = s;
    __syncthreads();
    float mean = (sm[0] + sm[1] + sm[2] + sm[3]) * (1.0f / 256.0f);
    wc[t] = v / mean;
}

// ---------------- normalize rows, emit bf16 i-panels + j-panels ----------------
__global__ void prep_normalize(const float* __restrict__ x1, const float* __restrict__ x2,
                               const float* __restrict__ wc,
                               ushort* __restrict__ an_i, ushort* __restrict__ bn_i,
                               ushort* __restrict__ pan0, ushort* __restrict__ pan1,
                               ushort* __restrict__ pan2, ushort* __restrict__ pan3) {
    int row = blockIdx.x;  // 0..16383
    int t = threadIdx.x;   // 0..255
    int r; float v;
    ushort *ip, *pa, *pb;
    if (row < N) { r = row;     v = x1[(size_t)r * D + t] * wc[t]; ip = an_i; pa = pan0; pb = pan3; }
    else         { r = row - N; v = x2[(size_t)r * D + t];         ip = bn_i; pa = pan1; pb = pan2; }
    float ss = v * v;
#pragma unroll
    for (int m = 1; m < 64; m <<= 1) ss += __shfl_xor(ss, m);
    __shared__ float sm[4];
    if ((t & 63) == 0) sm[t >> 6] = ss;
    __syncthreads();
    float denom = sqrtf(sm[0] + sm[1] + sm[2] + sm[3]) + 1e-12f;
    ushort b = bf16r(v / denom);
    ip[(size_t)r * D + t] = b;
    pa[(size_t)r * KP + t] = b;
    pb[(size_t)r * KP + t] = b;
    if (t < 16) {  // ext cols: pot=0 -> pterm=-1 -> hi=0xBF80, lo=0; cols 258..271 zero
        ushort e = (t == 0) ? (ushort)0xBF80 : (ushort)0;
        pa[(size_t)r * KP + 256 + t] = e;
        pb[(size_t)r * KP + 256 + t] = e;
    }
}

// ---------------- fused cost + softmin via MFMA (flash-style, no LDS) ----------------
// tasks: 0: fxx (j=an, pot=fxx)  1: gyy (j=bn, pot=gyy)  2: f (j=bn, pot=g)  3: g (j=an, pot=f)
// Swapped operands: A_op = j-side frags (streamed, L2-resident), B_op = i-side frags
// PINNED in registers via asm (compiler otherwise sinks the loads into the loop —
// R2/R3 showed VGPR_Count 104/48 vs the 136 needed; the pin defeats rematerialization).
// Block mapping keeps (task, split-pair) fixed per XCD (bx % 8): 2.2 MB j-working set < 4 MB L2.
__global__ __launch_bounds__(256, 2) void softmin_mfma(
    const ushort* __restrict__ an_i, const ushort* __restrict__ bn_i,
    const ushort* __restrict__ pan0, const ushort* __restrict__ pan1,
    const ushort* __restrict__ pan2, const ushort* __restrict__ pan3,
    float2* __restrict__ parts, float k1) {  // k1 = log2(e)/eps
    int bx = blockIdx.x;          // 512 blocks
    int k = bx & 7;               // XCD slot (heuristic)
    int q = bx >> 3;              // 0..63
    int task = k >> 1;
    int split = ((k & 1) << 1) | (q & 1);
    int rb = q >> 1;              // 0..31
    const ushort* jp; const ushort* ip;
    switch (task) {
        case 0:  jp = pan0; ip = an_i; break;
        case 1:  jp = pan1; ip = bn_i; break;
        case 2:  jp = pan2; ip = an_i; break;
        default: jp = pan3; ip = bn_i; break;
    }
    int t = threadIdx.x;
    int wave = t >> 6, lane = t & 63;
    int l31 = lane & 31, lh = lane >> 5;
    int i0 = rb * 256 + wave * 64;  // this wave: rows [i0, i0+64)

    // B_op (i-side) fragments, K=256 (16 chunks) + pot chunk, two 32-row sets
    short8 bi0[17], bi1[17];
    const ushort* ib = ip + (size_t)(i0 + l31) * D + lh * 8;
#pragma unroll
    for (int c = 0; c < 16; ++c) {
        bi0[c] = *(const short8*)(ib + c * 16);
        bi1[c] = *(const short8*)(ib + (size_t)32 * D + c * 16);
    }
    short8 pz = {};  // pot chunk: a_ext[i][256]=a_ext[i][257]=1.0
    if (lh == 0) { pz[0] = (short)0x3F80; pz[1] = (short)0x3F80; }
    bi0[16] = pz; bi1[16] = pz;

    float m0 = -INFINITY, s0 = 0.0f, m1 = -INFINITY, s1 = 0.0f;
    const ushort* jbase = jp + (size_t)(split * 2048 + l31) * KP + lh * 8;

    for (int js = 0; js < 64; ++js) {  // 32 j's per step, 2048 per split
        // Pin i-fragments: redefine each step so the compiler must keep them
        // live in VGPRs across the loop (no sinking/rematerialization).
#pragma unroll
        for (int c = 0; c < 17; ++c) {
            asm volatile("" : "+v"(bi0[c]), "+v"(bi1[c]));
        }
        const ushort* ar = jbase + (size_t)js * 32 * KP;
        f32x16 acc0 = {}; f32x16 acc1 = {};
#pragma unroll
        for (int c = 0; c < 17; ++c) {
            short8 af = *(const short8*)(ar + c * 16);
            acc0 = __builtin_amdgcn_mfma_f32_32x32x16_bf16(af, bi0[c], acc0, 0, 0, 0);
            acc1 = __builtin_amdgcn_mfma_f32_32x32x16_bf16(af, bi1[c], acc1, 0, 0, 0);
        }
        // acc = cos_sim + (pot_j - 1); online LSE in base-2, per lane (one row per set)
        {
            float tv[16];
#pragma unroll
            for (int r = 0; r < 16; ++r) tv[r] = acc0[r] * k1;
            float tm = tv[0];
#pragma unroll
            for (int r = 1; r < 16; ++r) tm = fmaxf(tm, tv[r]);
            float mn = fmaxf(m0, tm);
            float ad = 0.0f;
#pragma unroll
            for (int r = 0; r < 16; ++r) ad += fexp2(tv[r] - mn);
            s0 = s0 * fexp2(m0 - mn) + ad; m0 = mn;
        }
        {
            float tv[16];
#pragma unroll
            for (int r = 0; r < 16; ++r) tv[r] = acc1[r] * k1;
            float tm = tv[0];
#pragma unroll
            for (int r = 1; r < 16; ++r) tm = fmaxf(tm, tv[r]);
            float mn = fmaxf(m1, tm);
            float ad = 0.0f;
#pragma unroll
            for (int r = 0; r < 16; ++r) ad += fexp2(tv[r] - mn);
            s1 = s1 * fexp2(m1 - mn) + ad; m1 = mn;
        }
    }
    // lanes l and l+32 hold disjoint j-subsets of the same row: merge
    float mo = __shfl_xor(m0, 32), so = __shfl_xor(s0, 32);
    float M0 = fmaxf(m0, mo);
    float S0 = s0 * fexp2(m0 - M0) + so * fexp2(mo - M0);
    mo = __shfl_xor(m1, 32); so = __shfl_xor(s1, 32);
    float M1 = fmaxf(m1, mo);
    float S1 = s1 * fexp2(m1 - M1) + so * fexp2(mo - M1);
    if (lane < 32) {
        size_t r0 = (size_t)task * N + (i0 + l31);
        size_t r1 = r0 + 32;
        parts[r0 * 4 + split] = make_float2(M0, S0);
        parts[r1 * 4 + split] = make_float2(M1, S1);
    }
}

// ---------------- merge j-split partials -> new potentials + panel pot columns ----------------
__global__ void merge_pots(const float2* __restrict__ parts, float* __restrict__ pots,
                           ushort* __restrict__ pan0, ushort* __restrict__ pan1,
                           ushort* __restrict__ pan2, ushort* __restrict__ pan3,
                           float eps, float logw, int do_avg) {
    int id = blockIdx.x * 256 + threadIdx.x;  // 0..4N-1; id = task*N + row
    int task = id >> 13;
    int row = id & (N - 1);
    const float2* p = parts + (size_t)id * 4;
    float2 a = p[0], b = p[1], c = p[2], d = p[3];
    float M = fmaxf(fmaxf(a.x, b.x), fmaxf(c.x, d.x));
    float S = a.y * fexp2(a.x - M) + b.y * fexp2(b.x - M) +
              c.y * fexp2(c.x - M) + d.y * fexp2(d.x - M);
    float lse = LN2 * (M + flog2(S));      // natural-log LSE of (pot_j - C_ij)/eps
    float v = -eps * (logw + lse);
    if (do_avg && task < 2) v = 0.5f * (pots[id] + v);
    pots[id] = v;
    // panel pot columns for NEXT iteration: task0->pan0, task1->pan1,
    // task2 (f) -> pan3 (task3 streams f), task3 (g) -> pan2 (task2 streams g)
    ushort* pan;
    switch (task) {
        case 0:  pan = pan0; break;
        case 1:  pan = pan1; break;
        case 2:  pan = pan3; break;
        default: pan = pan2; break;
    }
    float pt = v - 1.0f;
    ushort hi = bf16r(pt);
    float lo = pt - bf16f(hi);
    pan[(size_t)row * KP + 256] = hi;
    pan[(size_t)row * KP + 257] = bf16r(lo);
}

// ---------------- final scalar reduce ----------------
__global__ void final_reduce(const float* __restrict__ pots, float* __restrict__ out) {
    int t = threadIdx.x;
    float s = 0.0f;
    for (int i = t; i < N; i += 256)
        s += (pots[2 * N + i] - pots[i]) + (pots[3 * N + i] - pots[N + i]);
#pragma unroll
    for (int m = 1; m < 64; m <<= 1) s += __shfl_xor(s, m);
    __shared__ float sm[4];
    if ((t & 63) == 0) sm[t >> 6] = s;
    __syncthreads();
    if (t == 0) out[0] = (sm[0] + sm[1] + sm[2] + sm[3]) * (1.0f / (float)N);
}

extern "C" void kernel_launch(void* const* d_in, const int* in_sizes, int n_in,
                              void* d_out, int out_size, void* d_ws, size_t ws_size,
                              hipStream_t stream) {
    const float* x1 = (const float*)d_in[0];
    const float* x2 = (const float*)d_in[1];
    const float* w  = (const float*)d_in[2];
    float* out = (float*)d_out;

    ushort* an_i = (ushort*)d_ws;                       // N*D bf16
    ushort* bn_i = an_i + (size_t)N * D;                // N*D
    ushort* pan0 = bn_i + (size_t)N * D;                // N*KP each
    ushort* pan1 = pan0 + (size_t)N * KP;
    ushort* pan2 = pan1 + (size_t)N * KP;
    ushort* pan3 = pan2 + (size_t)N * KP;
    float*  wc   = (float*)(pan3 + (size_t)N * KP);     // 256
    float*  pots = wc + 256;                            // 4N  (fxx,gyy,f,g)
    float2* parts = (float2*)(pots + 4 * N);            // 4N * 4 splits

    hipMemsetAsync(pots, 0, 4 * N * sizeof(float), stream);
    prep_wc<<<1, 256, 0, stream>>>(w, wc);
    prep_normalize<<<2 * N, 256, 0, stream>>>(x1, x2, wc, an_i, bn_i, pan0, pan1, pan2, pan3);

    const float eps_list[10] = {4.0f, 1.0f, 0.25f, 0.0625f, 0.015625f,
                                0.00390625f, 0.0025f, 0.0025f, 0.0025f, 0.0025f};
    const float logw = -logf((float)N);
    const float LOG2E = 1.4426950408889634f;
    for (int it = 0; it < 10; ++it) {
        softmin_mfma<<<512, 256, 0, stream>>>(an_i, bn_i, pan0, pan1, pan2, pan3,
                                              parts, LOG2E / eps_list[it]);
        merge_pots<<<4 * N / 256, 256, 0, stream>>>(parts, pots, pan0, pan1, pan2, pan3,
                                                    eps_list[it], logw, 1);
    }
    // final extrapolation at eps_final, no averaging
    softmin_mfma<<<512, 256, 0, stream>>>(an_i, bn_i, pan0, pan1, pan2, pan3,
                                          parts, LOG2E / 0.0025f);
    merge_pots<<<4 * N / 256, 256, 0, stream>>>(parts, pots, pan0, pan1, pan2, pan3,
                                                0.0025f, logw, 0);
    final_reduce<<<1, 256, 0, stream>>>(pots, out);
}

// Round 5
// 1662.130 us; speedup vs baseline: 2.0728x; 1.3203x over previous
//
#include <hip/hip_runtime.h>
#include <math.h>

#define N 8192
#define D 256
#define LN2 0.6931471805599453f
#define LDSROW 280           // shorts per LDS row: 560 B = 35 x 16B slots -> bank-group perm (3*l mod 8)
#define TSLOTS 1152          // 16-B slots per LDS buffer (1120 data+pad slots, rounded to 4.5 rounds)

typedef short short8 __attribute__((ext_vector_type(8)));
typedef float f32x16 __attribute__((ext_vector_type(16)));
typedef unsigned short ushort;

__device__ __forceinline__ float fexp2(float x) { return __builtin_amdgcn_exp2f(x); }
__device__ __forceinline__ float flog2(float x) { return __builtin_amdgcn_logf(x); }

__device__ __forceinline__ ushort bf16r(float x) {  // RNE f32 -> bf16
    unsigned int u = __float_as_uint(x);
    return (ushort)((u + 0x7FFF + ((u >> 16) & 1)) >> 16);
}

__device__ __forceinline__ void gl_lds16(const ushort* g, ushort* l) {
    __builtin_amdgcn_global_load_lds(
        (const __attribute__((address_space(1))) unsigned int*)g,
        (__attribute__((address_space(3))) unsigned int*)l, 16, 0, 0);
}

// ---------------- weight clip + renormalize ----------------
__global__ void prep_wc(const float* __restrict__ w, float* __restrict__ wc) {
    int t = threadIdx.x;  // 256
    float v = fminf(fmaxf(w[t], 0.0f), 2.0f);
    float s = v;
#pragma unroll
    for (int m = 1; m < 64; m <<= 1) s += __shfl_xor(s, m);
    __shared__ float sm[4];
    if ((t & 63) == 0) sm[t >> 6] = s;
    __syncthreads();
    float mean = (sm[0] + sm[1] + sm[2] + sm[3]) * (1.0f / 256.0f);
    wc[t] = v / mean;
}

// ---------------- normalize rows -> bf16 panels ----------------
__global__ void prep_normalize(const float* __restrict__ x1, const float* __restrict__ x2,
                               const float* __restrict__ wc,
                               ushort* __restrict__ an_i, ushort* __restrict__ bn_i) {
    int row = blockIdx.x;  // 0..16383
    int t = threadIdx.x;   // 0..255
    int r; float v; ushort* ip;
    if (row < N) { r = row;     v = x1[(size_t)r * D + t] * wc[t]; ip = an_i; }
    else         { r = row - N; v = x2[(size_t)r * D + t];         ip = bn_i; }
    float ss = v * v;
#pragma unroll
    for (int m = 1; m < 64; m <<= 1) ss += __shfl_xor(ss, m);
    __shared__ float sm[4];
    if ((t & 63) == 0) sm[t >> 6] = ss;
    __syncthreads();
    float denom = sqrtf(sm[0] + sm[1] + sm[2] + sm[3]) + 1e-12f;
    ip[(size_t)r * D + t] = bf16r(v / denom);
}

// ---------------- pots init: pot=0, potm1=-1 ----------------
__global__ void init_pots(float* __restrict__ pots, float* __restrict__ potm1) {
    int id = blockIdx.x * 256 + threadIdx.x;
    pots[id] = 0.0f;
    potm1[id] = -1.0f;
}

// ---------------- fused cost + softmin via MFMA, LDS-staged j-tiles ----------------
// tasks: 0: fxx (j=an,i=an)  1: gyy (j=bn,i=bn)  2: f (j=bn,i=an, pot=g)  3: g (j=an,i=bn, pot=f)
// potm1[task] holds (streamed-pot - 1) for the CONSUMER task (crossover written by merge).
// Per block: 256 i-rows (4 waves x 2 acc tiles), j-split of 2048 rows in 64 steps of 32.
// j-tile staged via global_load_lds (coalesced) into double-buffered padded LDS; i-frags in AGPRs.
__global__ __launch_bounds__(256, 2) void softmin_mfma(
    const ushort* __restrict__ an_i, const ushort* __restrict__ bn_i,
    const float* __restrict__ potm1,
    float2* __restrict__ parts, float k1) {  // k1 = log2(e)/eps
    int bx = blockIdx.x;          // 512 blocks
    int k = bx & 7;               // XCD slot: (task, split-pair) fixed per XCD
    int q = bx >> 3;              // 0..63
    int task = k >> 1;
    int split = ((k & 1) << 1) | (q & 1);
    int rb = q >> 1;              // 0..31
    const ushort* jp = (task == 0 || task == 3) ? an_i : bn_i;
    const ushort* ip = (task == 0 || task == 2) ? an_i : bn_i;
    const float* pm1 = potm1 + (size_t)task * N;

    int t = threadIdx.x;
    int wave = t >> 6, lane = t & 63;
    int l31 = lane & 31, lh = lane >> 5;
    int i0 = rb * 256 + wave * 64;  // this wave: rows [i0, i0+64)

    __shared__ ushort lbuf[2][TSLOTS * 8];

    // i-side (B_op) fragments, K=256 (16 chunks), two 32-row sets -> pin into AGPRs
    short8 bi0[16], bi1[16];
    {
        const ushort* ib = ip + (size_t)(i0 + l31) * D + lh * 8;
#pragma unroll
        for (int c = 0; c < 16; ++c) {
            bi0[c] = *(const short8*)(ib + c * 16);
            bi1[c] = *(const short8*)(ib + (size_t)32 * D + c * 16);
        }
    }
#pragma unroll
    for (int c = 0; c < 16; ++c) {
        asm volatile("" : "+a"(bi0[c]), "+a"(bi1[c]));  // force AGPR residency (off the VGPR budget)
    }

    const int jbase0 = split * 2048;

    // stage j-tile (32 rows x 256 shorts) into padded LDS buffer b
    auto stage = [&](int b, int js) {
        const ushort* gb = jp + (size_t)(jbase0 + js * 32) * D;
        ushort* lb = &lbuf[b][0];
#pragma unroll
        for (int r = 0; r < 5; ++r) {
            if (r == 4 && t >= 128) break;        // wave-uniform (waves 2,3 skip round 4)
            int s = r * 256 + t;                  // 16-B slot index
            int row = s / 35;                     // 35 slots per padded row
            int c = s - row * 35;
            row = row > 31 ? 31 : row;            // clamp pad slots to valid data
            c = c > 31 ? 31 : c;
            gl_lds16(gb + row * D + c * 8, lb + s * 8);
        }
    };

    float m0 = -INFINITY, s0 = 0.0f, m1 = -INFINITY, s1 = 0.0f;

    stage(0, 0);
    for (int js = 0; js < 64; ++js) {
        int cur = js & 1;
        __syncthreads();                 // drains cur's staging (issued last iter: ~free) + read/write fence
        if (js < 63) stage(cur ^ 1, js + 1);   // prefetch next tile: in flight during compute

        // pot terms for this step's 32 j-rows: per lane 16 j's = 4 consecutive float4s
        int j0 = jbase0 + js * 32;
        float pjk[16];
#pragma unroll
        for (int g = 0; g < 4; ++g) {
            float4 pv = *(const float4*)&pm1[j0 + 8 * g + 4 * lh];
            pjk[4 * g + 0] = pv.x * k1; pjk[4 * g + 1] = pv.y * k1;
            pjk[4 * g + 2] = pv.z * k1; pjk[4 * g + 3] = pv.w * k1;
        }

        const ushort* lrow = &lbuf[cur][l31 * LDSROW + lh * 8];
        f32x16 acc0 = {}; f32x16 acc1 = {};
#pragma unroll
        for (int c = 0; c < 16; ++c) {
            short8 af = *(const short8*)(lrow + c * 16);
            acc0 = __builtin_amdgcn_mfma_f32_32x32x16_bf16(af, bi0[c], acc0, 0, 0, 0);
            acc1 = __builtin_amdgcn_mfma_f32_32x32x16_bf16(af, bi1[c], acc1, 0, 0, 0);
        }

        // online LSE (base 2), one i-row per lane per tile: tv = (cos + pot - 1) * log2e/eps
        {
            float tv[16];
#pragma unroll
            for (int r = 0; r < 16; ++r) tv[r] = fmaf(acc0[r], k1, pjk[r]);
            float tm = tv[0];
#pragma unroll
            for (int r = 1; r < 16; ++r) tm = fmaxf(tm, tv[r]);
            float mn = fmaxf(m0, tm);
            float ad = 0.0f;
#pragma unroll
            for (int r = 0; r < 16; ++r) ad += fexp2(tv[r] - mn);
            s0 = s0 * fexp2(m0 - mn) + ad; m0 = mn;
        }
        {
            float tv[16];
#pragma unroll
            for (int r = 0; r < 16; ++r) tv[r] = fmaf(acc1[r], k1, pjk[r]);
            float tm = tv[0];
#pragma unroll
            for (int r = 1; r < 16; ++r) tm = fmaxf(tm, tv[r]);
            float mn = fmaxf(m1, tm);
            float ad = 0.0f;
#pragma unroll
            for (int r = 0; r < 16; ++r) ad += fexp2(tv[r] - mn);
            s1 = s1 * fexp2(m1 - mn) + ad; m1 = mn;
        }
    }
    // lanes l and l+32 hold disjoint j-subsets of the same i-row: merge
    float mo = __shfl_xor(m0, 32), so = __shfl_xor(s0, 32);
    float M0 = fmaxf(m0, mo);
    float S0 = s0 * fexp2(m0 - M0) + so * fexp2(mo - M0);
    mo = __shfl_xor(m1, 32); so = __shfl_xor(s1, 32);
    float M1 = fmaxf(m1, mo);
    float S1 = s1 * fexp2(m1 - M1) + so * fexp2(mo - M1);
    if (lane < 32) {
        size_t r0 = (size_t)task * N + (i0 + l31);
        size_t r1 = r0 + 32;
        parts[r0 * 4 + split] = make_float2(M0, S0);
        parts[r1 * 4 + split] = make_float2(M1, S1);
    }
}

// ---------------- merge j-split partials -> new potentials + consumer potm1 ----------------
__global__ void merge_pots(const float2* __restrict__ parts, float* __restrict__ pots,
                           float* __restrict__ potm1, float eps, float logw, int do_avg) {
    int id = blockIdx.x * 256 + threadIdx.x;  // id = task*N + row
    int task = id >> 13;
    int row = id & (N - 1);
    const float2* p = parts + (size_t)id * 4;
    float2 a = p[0], b = p[1], c = p[2], d = p[3];
    float M = fmaxf(fmaxf(a.x, b.x), fmaxf(c.x, d.x));
    float S = a.y * fexp2(a.x - M) + b.y * fexp2(b.x - M) +
              c.y * fexp2(c.x - M) + d.y * fexp2(d.x - M);
    float lse = LN2 * (M + flog2(S));      // natural-log LSE
    float v = -eps * (logw + lse);
    if (do_avg && task < 2) v = 0.5f * (pots[id] + v);
    pots[id] = v;
    // consumer mapping: fxx->task0, gyy->task1, f (task2) is streamed by task3, g (task3) by task2
    int ct = (task < 2) ? task : (5 - task);
    potm1[(size_t)ct * N + row] = v - 1.0f;
}

// ---------------- final scalar reduce ----------------
__global__ void final_reduce(const float* __restrict__ pots, float* __restrict__ out) {
    int t = threadIdx.x;
    float s = 0.0f;
    for (int i = t; i < N; i += 256)
        s += (pots[2 * N + i] - pots[i]) + (pots[3 * N + i] - pots[N + i]);
#pragma unroll
    for (int m = 1; m < 64; m <<= 1) s += __shfl_xor(s, m);
    __shared__ float sm[4];
    if ((t & 63) == 0) sm[t >> 6] = s;
    __syncthreads();
    if (t == 0) out[0] = (sm[0] + sm[1] + sm[2] + sm[3]) * (1.0f / (float)N);
}

extern "C" void kernel_launch(void* const* d_in, const int* in_sizes, int n_in,
                              void* d_out, int out_size, void* d_ws, size_t ws_size,
                              hipStream_t stream) {
    const float* x1 = (const float*)d_in[0];
    const float* x2 = (const float*)d_in[1];
    const float* w  = (const float*)d_in[2];
    float* out = (float*)d_out;

    ushort* an_i = (ushort*)d_ws;                       // N*D bf16
    ushort* bn_i = an_i + (size_t)N * D;                // N*D
    float*  wc   = (float*)(bn_i + (size_t)N * D);      // 256
    float*  pots = wc + 256;                            // 4N (fxx,gyy,f,g)
    float*  potm1 = pots + 4 * N;                       // 4N (consumer-indexed pot-1)
    float2* parts = (float2*)(potm1 + 4 * N);           // 4N * 4 splits

    prep_wc<<<1, 256, 0, stream>>>(w, wc);
    prep_normalize<<<2 * N, 256, 0, stream>>>(x1, x2, wc, an_i, bn_i);
    init_pots<<<4 * N / 256, 256, 0, stream>>>(pots, potm1);

    const float eps_list[10] = {4.0f, 1.0f, 0.25f, 0.0625f, 0.015625f,
                                0.00390625f, 0.0025f, 0.0025f, 0.0025f, 0.0025f};
    const float logw = -logf((float)N);
    const float LOG2E = 1.4426950408889634f;
    for (int it = 0; it < 10; ++it) {
        softmin_mfma<<<512, 256, 0, stream>>>(an_i, bn_i, potm1, parts, LOG2E / eps_list[it]);
        merge_pots<<<4 * N / 256, 256, 0, stream>>>(parts, pots, potm1,
                                                    eps_list[it], logw, 1);
    }
    // final extrapolation at eps_final, no averaging
    softmin_mfma<<<512, 256, 0, stream>>>(an_i, bn_i, potm1, parts, LOG2E / 0.0025f);
    merge_pots<<<4 * N / 256, 256, 0, stream>>>(parts, pots, potm1, 0.0025f, logw, 0);
    final_reduce<<<1, 256, 0, stream>>>(pots, out);
}